// Round 3
// baseline (243613.623 us; speedup 1.0000x reference)
//
#include <hip/hip_runtime.h>
#include <math.h>

#define NB 128
#define KPH 3
#define MAXPER 48
#define MAXTOK 144
#define LATENT 128
#define HD 512
#define NMEM 8
#define NH 8
#define VOC 8000
#define DHD 64
#define CT 145
#define NBLK 256
#define SCALE 0.125f

// ======================= setup kernels (run once, plain launches) ==========

__global__ void k_zero(float* __restrict__ p, int n) {
  int i = blockIdx.x * blockDim.x + threadIdx.x;
  if (i < n) p[i] = 0.0f;
}

__global__ void k_wz(const float* __restrict__ z_seq, const float* __restrict__ zw,
                     float* __restrict__ out) {
  int i = blockIdx.x * blockDim.x + threadIdx.x;
  if (i < NB * KPH * LATENT) out[i] = zw[i >> 7] * z_seq[i];
}

__global__ void k_copy(const float* __restrict__ src, float* __restrict__ dst, int n) {
  int i = blockIdx.x * blockDim.x + threadIdx.x;
  if (i < n) dst[i] = src[i];
}

// tiled fp32 GEMM (64col x 32row, 256 thr) for one-time setup GEMMs
__global__ __launch_bounds__(256) void k_gemm(
    const float* __restrict__ A, int lda,
    const float* __restrict__ W, int ldw, int K,
    float* __restrict__ out, int ostride)
{
  __shared__ float As[32][36];
  __shared__ float Ws[32][64];
  const int t = threadIdx.x;
  const int c0 = blockIdx.x * 64, b0 = blockIdx.y * 32;
  const int c = t & 63, g = t >> 6;
  float acc[8] = {0,0,0,0,0,0,0,0};
  const int ra = t >> 3, ka = (t & 7) << 2;
  for (int k0 = 0; k0 < K; k0 += 32) {
    const float4 a4 = *reinterpret_cast<const float4*>(A + (size_t)(b0 + ra) * lda + k0 + ka);
    As[ra][ka] = a4.x; As[ra][ka+1] = a4.y; As[ra][ka+2] = a4.z; As[ra][ka+3] = a4.w;
    #pragma unroll
    for (int e = 0; e < 8; e++) {
      int li = t + e * 256;
      Ws[li >> 6][li & 63] = W[(size_t)(k0 + (li >> 6)) * ldw + c0 + (li & 63)];
    }
    __syncthreads();
    #pragma unroll
    for (int kk = 0; kk < 32; kk++) {
      float wv = Ws[kk][c];
      #pragma unroll
      for (int i = 0; i < 8; i++) acc[i] += As[g*8+i][kk] * wv;
    }
    __syncthreads();
  }
  #pragma unroll
  for (int i = 0; i < 8; i++)
    out[(size_t)(b0 + g * 8 + i) * ostride + c0 + c] = acc[i];
}

__global__ void k_init(const float* __restrict__ zw, const float* __restrict__ temb,
                       float* __restrict__ XS, float* __restrict__ gf, int* __restrict__ iph,
                       int* __restrict__ cur, int* __restrict__ tip, int* __restrict__ pos,
                       int* __restrict__ done, int* __restrict__ act)
{
  int b = blockIdx.x;
  if (threadIdx.x == 0) {
    int a0 = zw[b*3+0] > 0.01f;
    act[b*3+0] = a0;
    act[b*3+1] = zw[b*3+1] > 0.01f;
    act[b*3+2] = zw[b*3+2] > 0.01f;
    cur[b] = 0; tip[b] = 0; pos[b] = 0; done[b] = !a0;
    gf[b] = a0 ? 1.0f : 0.0f; iph[b] = 0;
  }
  for (int c = threadIdx.x; c < HD; c += blockDim.x)
    XS[(size_t)b * 1024 + c] = temb[1 * HD + c];   // BOS = 1
}

// ======================= persistent decode (plain launch, grid barrier) ====

struct DecP {
  const float *temb, *Wq, *Wk, *Wv, *Wo, *Wco, *W1, *W2, *Wout;
  const float *MCK, *MCV, *WCAT;
  float *KC, *VC, *XS, *X2, *X3, *X, *Qb, *CQ, *CA, *H1, *PV, *GF;
  int *PI, *CUR, *TIP, *POS, *DONE, *IPH, *ACT;
  float *TOK, *GEN, *BND, *HID;
  unsigned *bar;
};

__device__ __forceinline__ void gsync(unsigned* bar, unsigned target) {
  __syncthreads();                       // all waves' mem ops drained (vmcnt)
  if (threadIdx.x == 0) {
    __threadfence();                     // release: L2 writeback, cross-XCD
    atomicAdd(bar, 1u);                  // device-scope by default on HIP
    while (__hip_atomic_load(bar, __ATOMIC_ACQUIRE, __HIP_MEMORY_SCOPE_AGENT) < target)
      __builtin_amdgcn_s_sleep(8);
    __threadfence();                     // acquire: invalidate L1/L2
  }
  __syncthreads();
}

__global__ __launch_bounds__(256, 1) void k_decode(DecP p) {
  __shared__ float As[32][36];
  __shared__ float Ws[32][64];
  __shared__ float rv[32][65];
  __shared__ float aux[4][224];          // per-wave: ql[64] + sc[160]
  __shared__ float sv[256];
  __shared__ int   si[256];
  __shared__ int   s_nxt;

  const int t = threadIdx.x;
  const int blk = blockIdx.x;
  unsigned tgt = 0;

  // 64col x 16row fp32 GEMM tile, 256 threads
  auto gemm16 = [&](int bx, int by, const float* A, int lda,
                    const float* W, int ldw, int K,
                    const float* R, int rs,
                    float* out, int os, int oo, int dogelu) {
    const int c0 = bx * 64, b0 = by * 16;
    const int c = t & 63, g = t >> 6;
    const int ra = t >> 4, ka = (t & 15) << 1;
    float acc[4] = {0,0,0,0};
    for (int k0 = 0; k0 < K; k0 += 32) {
      float2 a2 = *reinterpret_cast<const float2*>(A + (size_t)(b0 + ra) * lda + k0 + ka);
      As[ra][ka] = a2.x; As[ra][ka+1] = a2.y;
      #pragma unroll
      for (int e = 0; e < 8; e++) {
        int li = t + e * 256;
        Ws[li >> 6][li & 63] = W[(size_t)(k0 + (li >> 6)) * ldw + c0 + (li & 63)];
      }
      __syncthreads();
      #pragma unroll
      for (int kk = 0; kk < 32; kk++) {
        float wv = Ws[kk][c];
        #pragma unroll
        for (int i = 0; i < 4; i++) acc[i] += As[g*4+i][kk] * wv;
      }
      __syncthreads();
    }
    #pragma unroll
    for (int i = 0; i < 4; i++) {
      int b = b0 + g * 4 + i;
      float v = acc[i];
      if (R) v += R[(size_t)b * rs + c0 + c];
      if (dogelu) {
        float x3 = v * v * v;
        v = 0.5f * v * (1.0f + tanhf(0.7978845608028654f * (v + 0.044715f * x3)));
      }
      out[(size_t)b * os + oo + c0 + c] = v;
    }
  };

  // logits tile 64col x 32row + per-(b,tile) argmax partial
  auto logits_tile = [&](int bx, int by) {
    const int c0 = bx * 64, b0 = by * 32;
    const int c = t & 63, g = t >> 6;
    const int ra = t >> 3, ka = (t & 7) << 2;
    float acc[8] = {0,0,0,0,0,0,0,0};
    for (int k0 = 0; k0 < 512; k0 += 32) {
      float4 a4 = *reinterpret_cast<const float4*>(p.X + (size_t)(b0 + ra) * 512 + k0 + ka);
      As[ra][ka] = a4.x; As[ra][ka+1] = a4.y; As[ra][ka+2] = a4.z; As[ra][ka+3] = a4.w;
      #pragma unroll
      for (int e = 0; e < 8; e++) {
        int li = t + e * 256;
        Ws[li >> 6][li & 63] = p.Wout[(size_t)(k0 + (li >> 6)) * VOC + c0 + (li & 63)];
      }
      __syncthreads();
      #pragma unroll
      for (int kk = 0; kk < 32; kk++) {
        float wv = Ws[kk][c];
        #pragma unroll
        for (int i = 0; i < 8; i++) acc[i] += As[g*8+i][kk] * wv;
      }
      __syncthreads();
    }
    #pragma unroll
    for (int i = 0; i < 8; i++) rv[g*8+i][c] = acc[i];
    __syncthreads();
    if (t < 32) {
      float best = rv[t][0]; int bi = 0;
      for (int cc = 1; cc < 64; cc++) {        // serial -> first-index tie-break
        float v = rv[t][cc];
        if (v > best) { best = v; bi = cc; }
      }
      p.PV[(size_t)(b0 + t) * 125 + bx] = best;
      p.PI[(size_t)(b0 + t) * 125 + bx] = c0 + bi;
    }
    __syncthreads();
  };

  for (int s = 0; s < MAXTOK; s++) {
    // ---- A: Q,K,V projections (slot s) ----
    if (blk < 64)
      gemm16(blk & 7, blk >> 3, p.XS, 1024, p.Wq, 512, 512, nullptr, 0, p.Qb, 512, 0, 0);
    else if (blk < 128)
      gemm16((blk-64) & 7, (blk-64) >> 3, p.XS, 1024, p.Wk, 512, 512, nullptr, 0, p.KC, CT*512, s*512, 0);
    else if (blk < 192)
      gemm16((blk-128) & 7, (blk-128) >> 3, p.XS, 1024, p.Wv, 512, 512, nullptr, 0, p.VC, CT*512, s*512, 0);
    tgt += NBLK; gsync(p.bar, tgt);

    // ---- B: self-attention, T = s+1, one wave per (b,h) ----
    {
      const int T = s + 1;
      int lane = t & 63, w = t >> 6;
      int task = blk * 4 + w, b = task >> 3, h = task & 7;
      float* ql = aux[w];
      float* sc = aux[w] + 64;
      ql[lane] = p.Qb[(size_t)b * 512 + h * 64 + lane];
      __syncthreads();
      float lmax = -INFINITY;
      for (int s0 = lane; s0 < T; s0 += 64) {
        const float4* kp = reinterpret_cast<const float4*>(p.KC + ((size_t)b * CT + s0) * 512 + h * 64);
        float d = 0.0f;
        #pragma unroll
        for (int e = 0; e < 16; e++) {
          float4 k4 = kp[e];
          d += ql[4*e]*k4.x + ql[4*e+1]*k4.y + ql[4*e+2]*k4.z + ql[4*e+3]*k4.w;
        }
        d *= SCALE;
        sc[s0] = d;
        lmax = fmaxf(lmax, d);
      }
      #pragma unroll
      for (int off = 32; off; off >>= 1) lmax = fmaxf(lmax, __shfl_xor(lmax, off, 64));
      float lsum = 0.0f;
      for (int s0 = lane; s0 < T; s0 += 64) {
        float e = expf(sc[s0] - lmax);
        sc[s0] = e; lsum += e;
      }
      #pragma unroll
      for (int off = 32; off; off >>= 1) lsum += __shfl_xor(lsum, off, 64);
      __syncthreads();
      float inv = 1.0f / lsum;
      float acc = 0.0f;
      const float* vb = p.VC + (size_t)b * CT * 512 + h * 64 + lane;
      for (int s0 = 0; s0 < T; s0++) acc += sc[s0] * vb[(size_t)s0 * 512];
      p.XS[(size_t)b * 1024 + 512 + h * 64 + lane] = acc * inv;   // SA result
    }
    tgt += NBLK; gsync(p.bar, tgt);

    // ---- C: X2 = XIN + SA@Wo ; CQ = XIN@Wcq + SA@(Wo@Wcq) (K=1024 fused) ----
    if (blk < 64)
      gemm16(blk & 7, blk >> 3, p.XS + 512, 1024, p.Wo, 512, 512, p.XS, 1024, p.X2, 512, 0, 0);
    else if (blk < 128)
      gemm16((blk-64) & 7, (blk-64) >> 3, p.XS, 1024, p.WCAT, 512, 1024, nullptr, 0, p.CQ, 512, 0, 0);
    tgt += NBLK; gsync(p.bar, tgt);

    // ---- D: cross-attention, one block per b ----
    if (blk < NB) {
      int b = blk;
      float* cqs = &As[0][0];     // 512 floats
      float* scs = &rv[0][0];     // 64 floats
      cqs[t]       = p.CQ[(size_t)b * 512 + t];
      cqs[t + 256] = p.CQ[(size_t)b * 512 + t + 256];
      __syncthreads();
      float gate = p.GF[b];
      int ip = p.IPH[b];
      const float* mk = p.MCK + (size_t)(b * KPH + ip) * NMEM * 512;
      if (t < 64) {
        int h = t >> 3, m = t & 7;
        const float4* kp = reinterpret_cast<const float4*>(mk + m * 512 + h * 64);
        float d = 0.0f;
        #pragma unroll
        for (int e = 0; e < 16; e++) {
          float4 k4 = kp[e];
          d += cqs[h*64+4*e]*k4.x + cqs[h*64+4*e+1]*k4.y + cqs[h*64+4*e+2]*k4.z + cqs[h*64+4*e+3]*k4.w;
        }
        scs[t] = d * SCALE * gate;
      }
      __syncthreads();
      const float* mv = p.MCV + (size_t)(b * KPH + ip) * NMEM * 512;
      #pragma unroll
      for (int half = 0; half < 2; half++) {
        int c = t + half * 256;
        int h = c >> 6;
        float mx = scs[h*8];
        #pragma unroll
        for (int m = 1; m < 8; m++) mx = fmaxf(mx, scs[h*8+m]);
        float ee[8]; float sum = 0.0f;
        #pragma unroll
        for (int m = 0; m < 8; m++) { ee[m] = expf(scs[h*8+m] - mx); sum += ee[m]; }
        float a = 0.0f;
        #pragma unroll
        for (int m = 0; m < 8; m++) a += ee[m] * mv[(size_t)m * 512 + c];
        p.CA[(size_t)b * 512 + c] = gate * a / sum;
      }
    }
    tgt += NBLK; gsync(p.bar, tgt);

    // ---- E: X3 = X2 + CA@Wco ----
    if (blk < 64)
      gemm16(blk & 7, blk >> 3, p.CA, 512, p.Wco, 512, 512, p.X2, 512, p.X3, 512, 0, 0);
    tgt += NBLK; gsync(p.bar, tgt);

    // ---- F: H1 = gelu(X3@W1), N=2048 ----
    gemm16(blk & 31, blk >> 5, p.X3, 512, p.W1, 2048, 512, nullptr, 0, p.H1, 2048, 0, 1);
    tgt += NBLK; gsync(p.bar, tgt);

    // ---- G: X = X3 + H1@W2, K=2048 ----
    if (blk < 64)
      gemm16(blk & 7, blk >> 3, p.H1, 2048, p.W2, 512, 2048, p.X3, 512, p.X, 512, 0, 0);
    tgt += NBLK; gsync(p.bar, tgt);

    // ---- H: logits + argmax partials (500 tiles over 256 blocks) ----
    for (int id = blk; id < 500; id += NBLK) logits_tile(id % 125, id / 125);
    tgt += NBLK; gsync(p.bar, tgt);

    // ---- I: argmax finish + state machine + hiddens + next embedding ----
    if (blk < NB) {
      int b = blk;
      float v = -INFINITY; int idx = 0x7fffffff;
      if (t < 125) { v = p.PV[(size_t)b * 125 + t]; idx = p.PI[(size_t)b * 125 + t]; }
      sv[t] = v; si[t] = idx;
      __syncthreads();
      for (int s2 = 128; s2 > 0; s2 >>= 1) {
        if (t < s2) {
          float v2 = sv[t + s2]; int i2 = si[t + s2];
          if (v2 > sv[t] || (v2 == sv[t] && i2 < si[t])) { sv[t] = v2; si[t] = i2; }
        }
        __syncthreads();
      }
      if (t == 0) {
        int nxt = si[0]; s_nxt = nxt;
        int dn = p.DONE[b]; int live = !dn;
        int pp = p.POS[b], tp = p.TIP[b], cp = p.CUR[b];
        if (pp < MAXTOK) {
          p.TOK[(size_t)b * MAXTOK + pp] = live ? (float)nxt : 0.0f;
          p.GEN[(size_t)b * MAXTOK + pp] = live ? 1.0f : 0.0f;
        }
        pp += live; tp += live;
        int eos = (nxt == 2) && (tp >= 1);
        int sw = (eos || (tp >= MAXPER)) && live;
        cp += sw;
        if (sw) tp = 0;
        int cpc = cp < 2 ? cp : 2;
        if (sw && (cp < KPH)) p.BND[(size_t)b * KPH + cpc] = (float)pp;
        dn = dn || (cp >= KPH) || (sw && !p.ACT[b*3 + cpc]);
        p.CUR[b] = cp; p.TIP[b] = tp; p.POS[b] = pp; p.DONE[b] = dn;
        p.GF[b] = (p.ACT[b*3 + cpc] && !dn) ? 1.0f : 0.0f;
        p.IPH[b] = cpc;
      }
      __syncthreads();
      int nxt = s_nxt;
      #pragma unroll
      for (int rep = 0; rep < 2; rep++) {
        int c = t + rep * 256;
        p.XS[(size_t)b * 1024 + c] = p.temb[(size_t)nxt * 512 + c];
        p.HID[((size_t)s * NB + b) * 512 + c] = p.X[(size_t)b * 512 + c];
      }
    }
    tgt += NBLK; gsync(p.bar, tgt);
  }
}

// ======================= host ==============================================

extern "C" void kernel_launch(void* const* d_in, const int* in_sizes, int n_in,
                              void* d_out, int out_size, void* d_ws, size_t ws_size,
                              hipStream_t stream)
{
  const float* z_seq = (const float*)d_in[0];
  const float* z_w   = (const float*)d_in[1];
  const float* W_l2d = (const float*)d_in[2];
  const float* temb  = (const float*)d_in[3];
  const float* Wq  = (const float*)d_in[4];
  const float* Wk  = (const float*)d_in[5];
  const float* Wv  = (const float*)d_in[6];
  const float* Wo  = (const float*)d_in[7];
  const float* Wcq = (const float*)d_in[8];
  const float* Wck = (const float*)d_in[9];
  const float* Wcv = (const float*)d_in[10];
  const float* Wco = (const float*)d_in[11];
  const float* W1  = (const float*)d_in[12];
  const float* W2  = (const float*)d_in[13];
  const float* Wout= (const float*)d_in[14];

  float* fw = (float*)d_ws;
  size_t o = 64;   // first 64 floats: barrier
  auto alloc = [&](size_t n) { float* r = fw + o; o += (n + 63) & ~(size_t)63; return r; };
  float* MCK = alloc((size_t)NB*KPH*NMEM*HD);
  float* MCV = alloc((size_t)NB*KPH*NMEM*HD);
  float* MEM = alloc((size_t)NB*KPH*NMEM*HD);   // reused as WCAT after setup
  float* KC  = alloc((size_t)NB*CT*HD);
  float* VC  = alloc((size_t)NB*CT*HD);
  float* XS  = alloc((size_t)NB*1024);          // [XIN | SA]
  float* X2  = alloc((size_t)NB*HD);
  float* X3  = alloc((size_t)NB*HD);
  float* X   = alloc((size_t)NB*HD);
  float* Qb  = alloc((size_t)NB*HD);
  float* CQ  = alloc((size_t)NB*HD);
  float* CA  = alloc((size_t)NB*HD);
  float* H1  = alloc((size_t)NB*4*HD);
  float* WZ  = alloc((size_t)NB*KPH*LATENT);
  float* PV  = alloc((size_t)NB*125);
  float* GF  = alloc(NB);
  int* ib = (int*)alloc(0);
  size_t io = 0;
  auto ialloc = [&](size_t n) { int* r = ib + io; io += (n + 63) & ~(size_t)63; return r; };
  int* PI  = ialloc((size_t)NB*125);
  int* CUR = ialloc(NB);
  int* TIP = ialloc(NB);
  int* POS = ialloc(NB);
  int* DONE= ialloc(NB);
  int* IPH = ialloc(NB);
  int* ACT = ialloc(NB*KPH);

  float* WCAT = MEM;   // [Wcq ; Wo@Wcq]  (1024 x 512) — overlays MEM after setup

  float* out_f = (float*)d_out;
  float* TOK  = out_f;
  float* GEN  = out_f + NB*MAXTOK;
  float* BND  = out_f + 2*NB*MAXTOK;
  float* HID  = out_f + 2*NB*MAXTOK + NB*KPH;

  // ---- one-time setup (all plain kernels, graph-capture safe) ----
  k_zero<<<1, 64, 0, stream>>>(fw, 64);                                   // barrier
  int nz = 2*NB*MAXTOK + NB*KPH;
  k_zero<<<(nz + 255)/256, 256, 0, stream>>>(out_f, nz);                  // tok/gen/bnd
  k_wz<<<(NB*KPH*LATENT + 255)/256, 256, 0, stream>>>(z_seq, z_w, WZ);
  // memories[384,4096] = WZ @ W_l2d
  k_gemm<<<dim3(64,12),256,0,stream>>>(WZ, 128, W_l2d, 4096, 128, MEM, 4096);
  // MCK/MCV[3072,512] = memories @ Wck/Wcv
  k_gemm<<<dim3(8,96),256,0,stream>>>(MEM, 512, Wck, 512, 512, MCK, 512);
  k_gemm<<<dim3(8,96),256,0,stream>>>(MEM, 512, Wcv, 512, 512, MCV, 512);
  // WCAT rows 512..1023 = Wo@Wcq  (overwrites MEM — MEM no longer needed)
  k_gemm<<<dim3(8,16),256,0,stream>>>(Wo, 512, Wcq, 512, 512, WCAT + (size_t)512*512, 512);
  // WCAT rows 0..511 = Wcq
  k_copy<<<(512*512 + 255)/256, 256, 0, stream>>>(Wcq, WCAT, 512*512);
  k_init<<<NB,128,0,stream>>>(z_w, temb, XS, GF, IPH, CUR, TIP, POS, DONE, ACT);

  // ---- persistent decode: PLAIN launch (co-residency by capacity: 256 blocks,
  // 256 CUs, ~28KB LDS & 4 waves per block -> every block resident at dispatch)
  DecP prm;
  prm.temb = temb; prm.Wq = Wq; prm.Wk = Wk; prm.Wv = Wv; prm.Wo = Wo;
  prm.Wco = Wco; prm.W1 = W1; prm.W2 = W2; prm.Wout = Wout;
  prm.MCK = MCK; prm.MCV = MCV; prm.WCAT = WCAT;
  prm.KC = KC; prm.VC = VC; prm.XS = XS; prm.X2 = X2; prm.X3 = X3; prm.X = X;
  prm.Qb = Qb; prm.CQ = CQ; prm.CA = CA; prm.H1 = H1; prm.PV = PV; prm.GF = GF;
  prm.PI = PI; prm.CUR = CUR; prm.TIP = TIP; prm.POS = POS; prm.DONE = DONE;
  prm.IPH = IPH; prm.ACT = ACT;
  prm.TOK = TOK; prm.GEN = GEN; prm.BND = BND; prm.HID = HID;
  prm.bar = (unsigned*)d_ws;

  k_decode<<<dim3(NBLK), dim3(256), 0, stream>>>(prm);
}

// Round 4
// 43062.424 us; speedup vs baseline: 5.6572x; 5.6572x over previous
//
#include <hip/hip_runtime.h>
#include <math.h>

#define NB 128
#define KPH 3
#define MAXPER 48
#define MAXTOK 144
#define LATENT 128
#define HD 512
#define NMEM 8
#define NH 8
#define VOC 8000
#define CT 145
#define NBLK 512
#define SCALE 0.125f

// ---- device-coherent (agent-scope, sc1: bypass XCD L2, hit MALL) access ----
__device__ __forceinline__ float ldsc(const float* p) {
  return __hip_atomic_load(const_cast<float*>(p), __ATOMIC_RELAXED, __HIP_MEMORY_SCOPE_AGENT);
}
__device__ __forceinline__ void stsc(float* p, float v) {
  __hip_atomic_store(p, v, __ATOMIC_RELAXED, __HIP_MEMORY_SCOPE_AGENT);
}
__device__ __forceinline__ int ldsci(const int* p) {
  return __hip_atomic_load(const_cast<int*>(p), __ATOMIC_RELAXED, __HIP_MEMORY_SCOPE_AGENT);
}
__device__ __forceinline__ void stsci(int* p, int v) {
  __hip_atomic_store(p, v, __ATOMIC_RELAXED, __HIP_MEMORY_SCOPE_AGENT);
}

// ======================= setup kernels (run once) ==========================

__global__ void k_zero(float* __restrict__ p, int n) {
  int i = blockIdx.x * blockDim.x + threadIdx.x;
  if (i < n) p[i] = 0.0f;
}

__global__ void k_wz(const float* __restrict__ z_seq, const float* __restrict__ zw,
                     float* __restrict__ out) {
  int i = blockIdx.x * blockDim.x + threadIdx.x;
  if (i < NB * KPH * LATENT) out[i] = zw[i >> 7] * z_seq[i];
}

__global__ void k_copy(const float* __restrict__ src, float* __restrict__ dst, int n) {
  int i = blockIdx.x * blockDim.x + threadIdx.x;
  if (i < n) dst[i] = src[i];
}

__global__ __launch_bounds__(256) void k_gemm(
    const float* __restrict__ A, int lda,
    const float* __restrict__ W, int ldw, int K,
    float* __restrict__ out, int ostride)
{
  __shared__ float As[32][36];
  __shared__ float Ws[32][64];
  const int t = threadIdx.x;
  const int c0 = blockIdx.x * 64, b0 = blockIdx.y * 32;
  const int c = t & 63, g = t >> 6;
  float acc[8] = {0,0,0,0,0,0,0,0};
  const int ra = t >> 3, ka = (t & 7) << 2;
  for (int k0 = 0; k0 < K; k0 += 32) {
    const float4 a4 = *reinterpret_cast<const float4*>(A + (size_t)(b0 + ra) * lda + k0 + ka);
    As[ra][ka] = a4.x; As[ra][ka+1] = a4.y; As[ra][ka+2] = a4.z; As[ra][ka+3] = a4.w;
    #pragma unroll
    for (int e = 0; e < 8; e++) {
      int li = t + e * 256;
      Ws[li >> 6][li & 63] = W[(size_t)(k0 + (li >> 6)) * ldw + c0 + (li & 63)];
    }
    __syncthreads();
    #pragma unroll
    for (int kk = 0; kk < 32; kk++) {
      float wv = Ws[kk][c];
      #pragma unroll
      for (int i = 0; i < 8; i++) acc[i] += As[g*8+i][kk] * wv;
    }
    __syncthreads();
  }
  #pragma unroll
  for (int i = 0; i < 8; i++)
    out[(size_t)(b0 + g * 8 + i) * ostride + c0 + c] = acc[i];
}

__global__ void k_init(const float* __restrict__ zw, const float* __restrict__ temb,
                       float* __restrict__ XS, float* __restrict__ gf, int* __restrict__ iph,
                       int* __restrict__ cur, int* __restrict__ tip, int* __restrict__ pos,
                       int* __restrict__ done, int* __restrict__ act)
{
  int b = blockIdx.x;
  if (threadIdx.x == 0) {
    int a0 = zw[b*3+0] > 0.01f;
    act[b*3+0] = a0;
    act[b*3+1] = zw[b*3+1] > 0.01f;
    act[b*3+2] = zw[b*3+2] > 0.01f;
    cur[b] = 0; tip[b] = 0; pos[b] = 0; done[b] = !a0;
    gf[b] = a0 ? 1.0f : 0.0f; iph[b] = 0;
  }
  for (int c = threadIdx.x; c < HD; c += blockDim.x)
    XS[(size_t)b * 1024 + c] = temb[1 * HD + c];   // BOS = 1
}

// ======================= persistent decode =================================

struct DecP {
  const float *temb, *Wq, *Wk, *Wv, *Wo, *Wco, *W1, *W2, *Wout;
  const float *MCK, *MCV, *WCAT;
  float *KC, *VC, *XS, *X2, *X3, *X, *Qb, *CQ, *CA, *H1, *PV, *GF;
  int *PI, *CUR, *TIP, *POS, *DONE, *IPH, *ACT;
  float *TOK, *GEN, *BND, *HID;
  unsigned *bar;
};

// no-invalidate grid barrier: arrive on 8 spread counters, relaxed poll.
// __syncthreads drains vmcnt(0) so prior sc1 write-through stores are visible.
__device__ __forceinline__ void gsync(unsigned* bars, unsigned target) {
  __syncthreads();
  if (threadIdx.x == 0) {
    __hip_atomic_fetch_add(&bars[(blockIdx.x & 7) * 32], 1u,
                           __ATOMIC_RELAXED, __HIP_MEMORY_SCOPE_AGENT);
    while (true) {
      unsigned sum = 0;
      #pragma unroll
      for (int i = 0; i < 8; i++)
        sum += __hip_atomic_load(&bars[i * 32], __ATOMIC_RELAXED, __HIP_MEMORY_SCOPE_AGENT);
      if (sum >= target) break;
      __builtin_amdgcn_s_sleep(4);
    }
  }
  __syncthreads();
}

__global__ __launch_bounds__(256, 2) void k_decode(DecP p) {
  __shared__ float As8[8][33];
  __shared__ float As32[32][36];
  __shared__ float Ws[32][64];
  __shared__ float rv[32][65];
  __shared__ float aux[4][224];
  __shared__ float sv[256];
  __shared__ int   si[256];
  __shared__ int   s_nxt;

  const int t = threadIdx.x;
  const int blk = blockIdx.x;
  unsigned tgt = 0;

  // 64col x 8row fp32 GEMM tile, 256 thr, 1-deep K-slab prefetch.
  // A/R loads + out stores are device-coherent (sc1); W loads are L2-cached.
  auto gemm8 = [&](int bx, int by, const float* A, int lda,
                   const float* W, int ldw, int K,
                   const float* R, int rs,
                   float* out, int os, int oo, int dogelu) {
    const int c0 = bx * 64, b0 = by * 8;
    const int c = t & 63, g = t >> 6;
    const int ar = t >> 5, ac = t & 31;
    float acc0 = 0.f, acc1 = 0.f;
    const float* Ap = A + (size_t)(b0 + ar) * lda + ac;
    float a_nxt = ldsc(Ap);
    float w_nxt[8];
    #pragma unroll
    for (int e = 0; e < 8; e++) {
      int li = t + e * 256;
      w_nxt[e] = W[(size_t)(li >> 6) * ldw + c0 + (li & 63)];
    }
    for (int k0 = 0; k0 < K; k0 += 32) {
      As8[ar][ac] = a_nxt;
      #pragma unroll
      for (int e = 0; e < 8; e++) {
        int li = t + e * 256;
        Ws[li >> 6][li & 63] = w_nxt[e];
      }
      __syncthreads();
      if (k0 + 32 < K) {
        a_nxt = ldsc(Ap + k0 + 32);
        #pragma unroll
        for (int e = 0; e < 8; e++) {
          int li = t + e * 256;
          w_nxt[e] = W[(size_t)(k0 + 32 + (li >> 6)) * ldw + c0 + (li & 63)];
        }
      }
      #pragma unroll
      for (int kk = 0; kk < 32; kk++) {
        float wv = Ws[kk][c];
        acc0 += As8[g * 2 + 0][kk] * wv;
        acc1 += As8[g * 2 + 1][kk] * wv;
      }
      __syncthreads();
    }
    #pragma unroll
    for (int i = 0; i < 2; i++) {
      float v = (i == 0) ? acc0 : acc1;
      int b = b0 + g * 2 + i;
      if (R) v += ldsc(R + (size_t)b * rs + c0 + c);
      if (dogelu) {
        float x3 = v * v * v;
        v = 0.5f * v * (1.0f + tanhf(0.7978845608028654f * (v + 0.044715f * x3)));
      }
      stsc(out + (size_t)b * os + oo + c0 + c, v);
    }
  };

  // logits tile 64col x 32row + per-(b,tile) argmax partial, prefetched
  auto logits_tile = [&](int bx, int by) {
    const int c0 = bx * 64, b0 = by * 32;
    const int c = t & 63, g = t >> 6;
    const int ra = t >> 3, ka = (t & 7) << 2;
    float acc[8] = {0,0,0,0,0,0,0,0};
    const float* Ap = p.X + (size_t)(b0 + ra) * 512 + ka;
    float a_nxt[4], w_nxt[8];
    #pragma unroll
    for (int j = 0; j < 4; j++) a_nxt[j] = ldsc(Ap + j);
    #pragma unroll
    for (int e = 0; e < 8; e++) {
      int li = t + e * 256;
      w_nxt[e] = p.Wout[(size_t)(li >> 6) * VOC + c0 + (li & 63)];
    }
    for (int k0 = 0; k0 < 512; k0 += 32) {
      #pragma unroll
      for (int j = 0; j < 4; j++) As32[ra][ka + j] = a_nxt[j];
      #pragma unroll
      for (int e = 0; e < 8; e++) {
        int li = t + e * 256;
        Ws[li >> 6][li & 63] = w_nxt[e];
      }
      __syncthreads();
      if (k0 + 32 < 512) {
        #pragma unroll
        for (int j = 0; j < 4; j++) a_nxt[j] = ldsc(Ap + k0 + 32 + j);
        #pragma unroll
        for (int e = 0; e < 8; e++) {
          int li = t + e * 256;
          w_nxt[e] = p.Wout[(size_t)(k0 + 32 + (li >> 6)) * VOC + c0 + (li & 63)];
        }
      }
      #pragma unroll
      for (int kk = 0; kk < 32; kk++) {
        float wv = Ws[kk][c];
        #pragma unroll
        for (int i = 0; i < 8; i++) acc[i] += As32[g*8+i][kk] * wv;
      }
      __syncthreads();
    }
    #pragma unroll
    for (int i = 0; i < 8; i++) rv[g*8+i][c] = acc[i];
    __syncthreads();
    if (t < 32) {
      float best = rv[t][0]; int bi = 0;
      for (int cc = 1; cc < 64; cc++) {        // serial -> first-index tie-break
        float v = rv[t][cc];
        if (v > best) { best = v; bi = cc; }
      }
      stsc(&p.PV[(size_t)(b0 + t) * 125 + bx], best);
      stsci(&p.PI[(size_t)(b0 + t) * 125 + bx], c0 + bi);
    }
    __syncthreads();
  };

  for (int s = 0; s < MAXTOK; s++) {
    // ---- A: Q,K,V projections (slot s); KC/VC write-through (write-once) ----
    if (blk < 128)
      gemm8(blk & 7, blk >> 3, p.XS, 1024, p.Wq, 512, 512, nullptr, 0, p.Qb, 512, 0, 0);
    else if (blk < 256)
      gemm8((blk-128) & 7, (blk-128) >> 3, p.XS, 1024, p.Wk, 512, 512, nullptr, 0, p.KC, CT*512, s*512, 0);
    else if (blk < 384)
      gemm8((blk-256) & 7, (blk-256) >> 3, p.XS, 1024, p.Wv, 512, 512, nullptr, 0, p.VC, CT*512, s*512, 0);
    tgt += NBLK; gsync(p.bar, tgt);

    // ---- B: self-attention, T = s+1, one wave per (b,h); KC/VC cached ----
    if (blk < 256) {
      const int T = s + 1;
      int lane = t & 63, w = t >> 6;
      int task = blk * 4 + w, b = task >> 3, h = task & 7;
      float* ql = aux[w];
      float* sc = aux[w] + 64;
      ql[lane] = ldsc(&p.Qb[(size_t)b * 512 + h * 64 + lane]);
      __syncthreads();
      float lmax = -INFINITY;
      for (int s0 = lane; s0 < T; s0 += 64) {
        const float4* kp = reinterpret_cast<const float4*>(p.KC + ((size_t)b * CT + s0) * 512 + h * 64);
        float d = 0.0f;
        #pragma unroll
        for (int e = 0; e < 16; e++) {
          float4 k4 = kp[e];
          d += ql[4*e]*k4.x + ql[4*e+1]*k4.y + ql[4*e+2]*k4.z + ql[4*e+3]*k4.w;
        }
        d *= SCALE;
        sc[s0] = d;
        lmax = fmaxf(lmax, d);
      }
      #pragma unroll
      for (int off = 32; off; off >>= 1) lmax = fmaxf(lmax, __shfl_xor(lmax, off, 64));
      float lsum = 0.0f;
      for (int s0 = lane; s0 < T; s0 += 64) {
        float e = expf(sc[s0] - lmax);
        sc[s0] = e; lsum += e;
      }
      #pragma unroll
      for (int off = 32; off; off >>= 1) lsum += __shfl_xor(lsum, off, 64);
      __syncthreads();
      float inv = 1.0f / lsum;
      float acc = 0.0f;
      const float* vb = p.VC + (size_t)b * CT * 512 + h * 64 + lane;
      for (int s0 = 0; s0 < T; s0++) acc += sc[s0] * vb[(size_t)s0 * 512];
      stsc(&p.XS[(size_t)b * 1024 + 512 + h * 64 + lane], acc * inv);
    }
    tgt += NBLK; gsync(p.bar, tgt);

    // ---- C: X2 = XIN + SA@Wo ; CQ = [XIN|SA] @ WCAT (K=1024) ----
    if (blk < 128)
      gemm8(blk & 7, blk >> 3, p.XS + 512, 1024, p.Wo, 512, 512, p.XS, 1024, p.X2, 512, 0, 0);
    else if (blk < 256)
      gemm8((blk-128) & 7, (blk-128) >> 3, p.XS, 1024, p.WCAT, 512, 1024, nullptr, 0, p.CQ, 512, 0, 0);
    tgt += NBLK; gsync(p.bar, tgt);

    // ---- D: cross-attention, one block per b ----
    if (blk < NB) {
      int b = blk;
      float* cqs = &As32[0][0];     // 512 floats
      float* scs = &rv[0][0];       // 64 floats
      cqs[t]       = ldsc(&p.CQ[(size_t)b * 512 + t]);
      cqs[t + 256] = ldsc(&p.CQ[(size_t)b * 512 + t + 256]);
      __syncthreads();
      float gate = ldsc(&p.GF[b]);
      int ip = ldsci(&p.IPH[b]);
      const float* mk = p.MCK + (size_t)(b * KPH + ip) * NMEM * 512;
      if (t < 64) {
        int h = t >> 3, m = t & 7;
        const float4* kp = reinterpret_cast<const float4*>(mk + m * 512 + h * 64);
        float d = 0.0f;
        #pragma unroll
        for (int e = 0; e < 16; e++) {
          float4 k4 = kp[e];
          d += cqs[h*64+4*e]*k4.x + cqs[h*64+4*e+1]*k4.y + cqs[h*64+4*e+2]*k4.z + cqs[h*64+4*e+3]*k4.w;
        }
        scs[t] = d * SCALE * gate;
      }
      __syncthreads();
      const float* mv = p.MCV + (size_t)(b * KPH + ip) * NMEM * 512;
      #pragma unroll
      for (int half = 0; half < 2; half++) {
        int c = t + half * 256;
        int h = c >> 6;
        float mx = scs[h*8];
        #pragma unroll
        for (int m = 1; m < 8; m++) mx = fmaxf(mx, scs[h*8+m]);
        float ee[8]; float sum = 0.0f;
        #pragma unroll
        for (int m = 0; m < 8; m++) { ee[m] = expf(scs[h*8+m] - mx); sum += ee[m]; }
        float a = 0.0f;
        #pragma unroll
        for (int m = 0; m < 8; m++) a += ee[m] * mv[(size_t)m * 512 + c];
        stsc(&p.CA[(size_t)b * 512 + c], gate * a / sum);
      }
    }
    tgt += NBLK; gsync(p.bar, tgt);

    // ---- E: X3 = X2 + CA@Wco ----
    if (blk < 128)
      gemm8(blk & 7, blk >> 3, p.CA, 512, p.Wco, 512, 512, p.X2, 512, p.X3, 512, 0, 0);
    tgt += NBLK; gsync(p.bar, tgt);

    // ---- F: H1 = gelu(X3@W1), N=2048, all 512 blocks ----
    gemm8(blk & 31, blk >> 5, p.X3, 512, p.W1, 2048, 512, nullptr, 0, p.H1, 2048, 0, 1);
    tgt += NBLK; gsync(p.bar, tgt);

    // ---- G: X = X3 + H1@W2, K=2048 ----
    if (blk < 128)
      gemm8(blk & 7, blk >> 3, p.H1, 2048, p.W2, 512, 2048, p.X3, 512, p.X, 512, 0, 0);
    tgt += NBLK; gsync(p.bar, tgt);

    // ---- H: logits + argmax partials, 500 tiles, one per block ----
    if (blk < 500) logits_tile(blk % 125, blk / 125);
    tgt += NBLK; gsync(p.bar, tgt);

    // ---- I: argmax finish + state machine + hiddens + next embedding ----
    if (blk < NB) {
      int b = blk;
      float v = -INFINITY; int idx = 0x7fffffff;
      if (t < 125) { v = ldsc(&p.PV[(size_t)b * 125 + t]); idx = ldsci(&p.PI[(size_t)b * 125 + t]); }
      sv[t] = v; si[t] = idx;
      __syncthreads();
      for (int s2 = 128; s2 > 0; s2 >>= 1) {
        if (t < s2) {
          float v2 = sv[t + s2]; int i2 = si[t + s2];
          if (v2 > sv[t] || (v2 == sv[t] && i2 < si[t])) { sv[t] = v2; si[t] = i2; }
        }
        __syncthreads();
      }
      if (t == 0) {
        int nxt = si[0]; s_nxt = nxt;
        int dn = p.DONE[b]; int live = !dn;
        int pp = p.POS[b], tp = p.TIP[b], cp = p.CUR[b];
        if (pp < MAXTOK) {
          p.TOK[(size_t)b * MAXTOK + pp] = live ? (float)nxt : 0.0f;
          p.GEN[(size_t)b * MAXTOK + pp] = live ? 1.0f : 0.0f;
        }
        pp += live; tp += live;
        int eos = (nxt == 2) && (tp >= 1);
        int sw = (eos || (tp >= MAXPER)) && live;
        cp += sw;
        if (sw) tp = 0;
        int cpc = cp < 2 ? cp : 2;
        if (sw && (cp < KPH)) p.BND[(size_t)b * KPH + cpc] = (float)pp;
        dn = dn || (cp >= KPH) || (sw && !p.ACT[b*3 + cpc]);
        p.CUR[b] = cp; p.TIP[b] = tp; p.POS[b] = pp; p.DONE[b] = dn;
        stsc(&p.GF[b], (p.ACT[b*3 + cpc] && !dn) ? 1.0f : 0.0f);
        stsci(&p.IPH[b], cpc);
      }
      __syncthreads();
      int nxt = s_nxt;
      #pragma unroll
      for (int rep = 0; rep < 2; rep++) {
        int c = t + rep * 256;
        stsc(&p.XS[(size_t)b * 1024 + c], p.temb[(size_t)nxt * 512 + c]);
        p.HID[((size_t)s * NB + b) * 512 + c] = ldsc(&p.X[(size_t)b * 512 + c]);
      }
    }
    tgt += NBLK; gsync(p.bar, tgt);
  }
}

// ======================= host ==============================================

extern "C" void kernel_launch(void* const* d_in, const int* in_sizes, int n_in,
                              void* d_out, int out_size, void* d_ws, size_t ws_size,
                              hipStream_t stream)
{
  const float* z_seq = (const float*)d_in[0];
  const float* z_w   = (const float*)d_in[1];
  const float* W_l2d = (const float*)d_in[2];
  const float* temb  = (const float*)d_in[3];
  const float* Wq  = (const float*)d_in[4];
  const float* Wk  = (const float*)d_in[5];
  const float* Wv  = (const float*)d_in[6];
  const float* Wo  = (const float*)d_in[7];
  const float* Wcq = (const float*)d_in[8];
  const float* Wck = (const float*)d_in[9];
  const float* Wcv = (const float*)d_in[10];
  const float* Wco = (const float*)d_in[11];
  const float* W1  = (const float*)d_in[12];
  const float* W2  = (const float*)d_in[13];
  const float* Wout= (const float*)d_in[14];

  float* fw = (float*)d_ws;
  size_t o = 256;   // first 256 words: spread barrier counters
  auto alloc = [&](size_t n) { float* r = fw + o; o += (n + 63) & ~(size_t)63; return r; };
  float* MCK = alloc((size_t)NB*KPH*NMEM*HD);
  float* MCV = alloc((size_t)NB*KPH*NMEM*HD);
  float* MEM = alloc((size_t)NB*KPH*NMEM*HD);   // reused as WCAT after setup
  float* KC  = alloc((size_t)NB*CT*HD);
  float* VC  = alloc((size_t)NB*CT*HD);
  float* XS  = alloc((size_t)NB*1024);          // [XIN | SA]
  float* X2  = alloc((size_t)NB*HD);
  float* X3  = alloc((size_t)NB*HD);
  float* X   = alloc((size_t)NB*HD);
  float* Qb  = alloc((size_t)NB*HD);
  float* CQ  = alloc((size_t)NB*HD);
  float* CA  = alloc((size_t)NB*HD);
  float* H1  = alloc((size_t)NB*4*HD);
  float* WZ  = alloc((size_t)NB*KPH*LATENT);
  float* PV  = alloc((size_t)NB*125);
  float* GF  = alloc(NB);
  int* ib = (int*)alloc(0);
  size_t io = 0;
  auto ialloc = [&](size_t n) { int* r = ib + io; io += (n + 63) & ~(size_t)63; return r; };
  int* PI  = ialloc((size_t)NB*125);
  int* CUR = ialloc(NB);
  int* TIP = ialloc(NB);
  int* POS = ialloc(NB);
  int* DONE= ialloc(NB);
  int* IPH = ialloc(NB);
  int* ACT = ialloc(NB*KPH);

  float* WCAT = MEM;   // [Wcq ; Wo@Wcq]  (1024 x 512) — overlays MEM after setup

  float* out_f = (float*)d_out;
  float* TOK  = out_f;
  float* GEN  = out_f + NB*MAXTOK;
  float* BND  = out_f + 2*NB*MAXTOK;
  float* HID  = out_f + 2*NB*MAXTOK + NB*KPH;

  // ---- one-time setup (plain kernels; dispatch boundaries give coherence) ----
  k_zero<<<1, 256, 0, stream>>>(fw, 256);                                 // barrier
  int nz = 2*NB*MAXTOK + NB*KPH;
  k_zero<<<(nz + 255)/256, 256, 0, stream>>>(out_f, nz);                  // tok/gen/bnd
  k_wz<<<(NB*KPH*LATENT + 255)/256, 256, 0, stream>>>(z_seq, z_w, WZ);
  k_gemm<<<dim3(64,12),256,0,stream>>>(WZ, 128, W_l2d, 4096, 128, MEM, 4096);
  k_gemm<<<dim3(8,96),256,0,stream>>>(MEM, 512, Wck, 512, 512, MCK, 512);
  k_gemm<<<dim3(8,96),256,0,stream>>>(MEM, 512, Wcv, 512, 512, MCV, 512);
  k_gemm<<<dim3(8,16),256,0,stream>>>(Wo, 512, Wcq, 512, 512, WCAT + (size_t)512*512, 512);
  k_copy<<<(512*512 + 255)/256, 256, 0, stream>>>(Wcq, WCAT, 512*512);
  k_init<<<NB,128,0,stream>>>(z_w, temb, XS, GF, IPH, CUR, TIP, POS, DONE, ACT);

  // ---- persistent decode: plain launch; 512 blocks, 2/CU co-resident ----
  DecP prm;
  prm.temb = temb; prm.Wq = Wq; prm.Wk = Wk; prm.Wv = Wv; prm.Wo = Wo;
  prm.Wco = Wco; prm.W1 = W1; prm.W2 = W2; prm.Wout = Wout;
  prm.MCK = MCK; prm.MCV = MCV; prm.WCAT = WCAT;
  prm.KC = KC; prm.VC = VC; prm.XS = XS; prm.X2 = X2; prm.X3 = X3; prm.X = X;
  prm.Qb = Qb; prm.CQ = CQ; prm.CA = CA; prm.H1 = H1; prm.PV = PV; prm.GF = GF;
  prm.PI = PI; prm.CUR = CUR; prm.TIP = TIP; prm.POS = POS; prm.DONE = DONE;
  prm.IPH = IPH; prm.ACT = ACT;
  prm.TOK = TOK; prm.GEN = GEN; prm.BND = BND; prm.HID = HID;
  prm.bar = (unsigned*)d_ws;

  k_decode<<<dim3(NBLK), dim3(256), 0, stream>>>(prm);
}